// Round 1
// baseline (774.886 us; speedup 1.0000x reference)
//
#include <hip/hip_runtime.h>
#include <hip/hip_bf16.h>
#include <stdint.h>

typedef __bf16 bf16_t;
typedef bf16_t bf16x8 __attribute__((ext_vector_type(8)));
typedef bf16_t bf16x4 __attribute__((ext_vector_type(4)));
typedef float floatx4 __attribute__((ext_vector_type(4)));
typedef uint32_t uint32x4 __attribute__((ext_vector_type(4)));

#define B_  64
#define SQ  1024
#define SK  1024
#define D_  256
#define DV  256
#define TK  32
#define NT  32
#define SCALE_F 0.0625f
#define NMASK   (-1.0e9f)
#define KEEP_F  (1.0f/0.9f)
#define THRESH  0.1f
#define DEFER_THR 3.0f   // skip o_acc rescale unless row-max grows by > this (p <= e^3, fine in bf16)

#define AS1(p) ((const __attribute__((address_space(1))) uint32_t*)(p))
#define AS3(p) ((__attribute__((address_space(3))) uint32_t*)(p))

#define RAW_BARRIER() __asm__ volatile("s_barrier" ::: "memory")
#define WAIT_VM(N)    __asm__ volatile("s_waitcnt vmcnt(" #N ")" ::: "memory")
#define WAIT_LGKM0()  __asm__ volatile("s_waitcnt lgkmcnt(0)" ::: "memory")

__device__ __forceinline__ void gload16(const void* g, void* lds) {
    // async global->LDS, 16B/lane; LDS base is wave-uniform, HW adds lane*16
    __builtin_amdgcn_global_load_lds(AS1(g), AS3(lds), 16, 0, 0);
}

template<int CTRL>
__device__ __forceinline__ float dpp_f(float x) {
    int y = __builtin_amdgcn_update_dpp(0, __float_as_int(x), CTRL, 0xF, 0xF, true);
    return __int_as_float(y);
}
// reductions over 16 contiguous lanes (one DPP "row") — VALU pipe, no LDS
__device__ __forceinline__ float rowsum16(float v) {
    v += dpp_f<0x128>(v);   // row_ror:8
    v += dpp_f<0x124>(v);   // row_ror:4
    v += dpp_f<0x4E>(v);    // quad_perm(2,3,0,1)
    v += dpp_f<0xB1>(v);    // quad_perm(1,0,3,2)
    return v;
}
__device__ __forceinline__ float rowmax16(float v) {
    v = fmaxf(v, dpp_f<0x128>(v));
    v = fmaxf(v, dpp_f<0x124>(v));
    v = fmaxf(v, dpp_f<0x4E>(v));
    v = fmaxf(v, dpp_f<0xB1>(v));
    return v;
}

// ---------------- pre-pass ----------------
// bid <  2048 : K fp32 -> bf16 swizzled tiles
// bid <  4096 : V fp32 -> bf16 transposed swizzled tiles
// bid >= 4096 : drop_u fp32 -> keep-bit mask. word[(b*SQ+row)*32 + kt] bit j = (du[b][row][kt*32+j] >= 0.1)
__global__ __launch_bounds__(256) void prepass(
    const float* __restrict__ k, const float* __restrict__ v, const float* __restrict__ du,
    bf16_t* __restrict__ ktiles, bf16_t* __restrict__ vtiles, uint32_t* __restrict__ dubits)
{
    __shared__ bf16_t Vls[32 * 258];   // padded transpose staging
    const int bid = blockIdx.x;
    const int tid = threadIdx.x;
    if (bid < 2048) {
        const int r = tid >> 3;
        const float* src = k + ((size_t)(bid * 32 + r)) * D_ + (tid & 7) * 32;
        char* dst = (char*)ktiles + ((size_t)bid) * 16384;
        #pragma unroll
        for (int gl = 0; gl < 4; ++gl) {
            float4 a = *(const float4*)(src + gl * 8);
            float4 b4 = *(const float4*)(src + gl * 8 + 4);
            bf16x8 f;
            f[0]=(bf16_t)a.x;  f[1]=(bf16_t)a.y;  f[2]=(bf16_t)a.z;  f[3]=(bf16_t)a.w;
            f[4]=(bf16_t)b4.x; f[5]=(bf16_t)b4.y; f[6]=(bf16_t)b4.z; f[7]=(bf16_t)b4.w;
            int g = (tid & 7) * 4 + gl;
            *(bf16x8*)(dst + r * 512 + ((g ^ (r & 7)) * 16)) = f;
        }
    } else if (bid < 4096) {
        const int bid2 = bid - 2048;
        const int kk = tid >> 3, dv0 = (tid & 7) * 32;
        const float* src = v + ((size_t)(bid2 * 32 + kk)) * DV + dv0;
        #pragma unroll
        for (int j = 0; j < 8; ++j) {
            float4 a = *(const float4*)(src + j * 4);
            bf16x4 f4;
            f4[0]=(bf16_t)a.x; f4[1]=(bf16_t)a.y; f4[2]=(bf16_t)a.z; f4[3]=(bf16_t)a.w;
            *(bf16x4*)(&Vls[kk * 258 + dv0 + j * 4]) = f4;
        }
        __syncthreads();
        char* dst = (char*)vtiles + ((size_t)bid2) * 16384;
        #pragma unroll
        for (int c = 0; c < 4; ++c) {
            int dv = c * 64 + (tid >> 2);
            int gphys = tid & 3;
            int glog = gphys ^ ((dv >> 1) & 3);
            bf16x8 f;
            #pragma unroll
            for (int jj = 0; jj < 8; ++jj) f[jj] = Vls[(glog * 8 + jj) * 258 + dv];
            *(bf16x8*)(dst + dv * 64 + gphys * 16) = f;
        }
    } else {
        // dropout bit-pack: 2048 blocks x 256 threads x 4 words; each word = 32 consecutive k
        const int w0 = (bid - 4096) * 1024 + tid * 4;
        const float* src = du + (size_t)w0 * 32;
        uint32x4 bits;
        #pragma unroll
        for (int j = 0; j < 4; ++j) {
            uint32_t m = 0;
            #pragma unroll
            for (int e = 0; e < 32; e += 4) {
                float4 f = *(const float4*)(src + j * 32 + e);
                m |= (f.x >= THRESH ? 1u : 0u) << e;
                m |= (f.y >= THRESH ? 1u : 0u) << (e + 1);
                m |= (f.z >= THRESH ? 1u : 0u) << (e + 2);
                m |= (f.w >= THRESH ? 1u : 0u) << (e + 3);
            }
            bits[j] = m;
        }
        *(uint32x4*)(dubits + w0) = bits;
    }
}

// ---------------- main fused attention ----------------
// LDS: Ks 16KB @0 | Vt 16KB @16384 | Ps 4KB @32768  = 36KB -> 4 blocks/CU (grid 1024 = 256 CU x 4, no tail)
__global__ __launch_bounds__(256, 4) void attn_main(
    const float* __restrict__ q, const int* __restrict__ mask,
    const uint32_t* __restrict__ dubits, const bf16_t* __restrict__ ktiles,
    const bf16_t* __restrict__ vtiles, float* __restrict__ out)
{
    __shared__ char smem[36864];
    char* KsB = smem;
    char* VtB = smem + 16384;
    char* PsB = smem + 32768;

    const int bid  = blockIdx.x;
    const int b    = bid >> 4;
    const int qt   = bid & 15;
    const int tid  = threadIdx.x;
    const int wave = tid >> 6;
    const int lane = tid & 63;
    const int col  = lane & 15;
    const int quad = lane >> 4;

    // Q fragments (A-layout), SCALE folded in before bf16 cvt
    bf16x8 qf[8];
    {
        const float* qp = q + ((size_t)(b*SQ + qt*64 + wave*16 + col))*D_ + quad*8;
        #pragma unroll
        for (int c = 0; c < 8; ++c) {
            float4 a  = *(const float4*)(qp + c*32);
            float4 b4 = *(const float4*)(qp + c*32 + 4);
            bf16x8 f;
            f[0]=(bf16_t)(a.x*SCALE_F);  f[1]=(bf16_t)(a.y*SCALE_F);
            f[2]=(bf16_t)(a.z*SCALE_F);  f[3]=(bf16_t)(a.w*SCALE_F);
            f[4]=(bf16_t)(b4.x*SCALE_F); f[5]=(bf16_t)(b4.y*SCALE_F);
            f[6]=(bf16_t)(b4.z*SCALE_F); f[7]=(bf16_t)(b4.w*SCALE_F);
            qf[c] = f;
        }
    }

    floatx4 o_acc[16];
    #pragma unroll
    for (int i = 0; i < 16; ++i) o_acc[i] = (floatx4){0.f,0.f,0.f,0.f};
    float m_i[4] = {-1e30f,-1e30f,-1e30f,-1e30f};
    float l_i[4] = {0.f,0.f,0.f,0.f};

    const size_t tbase = (size_t)(b * NT) * 16384;
    // per-lane dropout-bit base: rows wave*16 + quad*4 + i, one word per tile
    const uint32_t* dub = dubits + ((size_t)(b*SQ + qt*64 + wave*16 + quad*4)) * 32;

    // --- staging issue helpers (4 waves share each tile; 4/4 instrs per wave) ---
    #define ISSUE_K(t) do { \
        const char* g_ = (const char*)ktiles + tbase + (size_t)(t)*16384 + wave*4096 + lane*16; \
        char* l_ = KsB + wave*4096; \
        gload16(g_, l_); gload16(g_+1024, l_+1024); \
        gload16(g_+2048, l_+2048); gload16(g_+3072, l_+3072); } while(0)

    #define ISSUE_V(t) do { \
        const char* g_ = (const char*)vtiles + tbase + (size_t)(t)*16384 + wave*4096 + lane*16; \
        char* l_ = VtB + wave*4096; \
        gload16(g_, l_); gload16(g_+1024, l_+1024); \
        gload16(g_+2048, l_+2048); gload16(g_+3072, l_+3072); } while(0)

    // preamble: tile 0 in flight  (order: Ks, dubits, mask, Vt)
    ISSUE_K(0);
    uint32_t dwc[4];
    #pragma unroll
    for (int i = 0; i < 4; ++i) dwc[i] = dub[i*32 + 0];
    int mcur0 = mask[b*SK + col];
    int mcur1 = mask[b*SK + 16 + col];
    ISSUE_V(0);

    for (int kt = 0; kt < NT; ++kt) {
        const int tn = (kt + 1 < NT) ? kt + 1 : NT - 1;   // clamp -> constant vmcnt counts

        WAIT_VM(4);          // Ks[kt], dubits[kt], mask landed; Vt[kt] still in flight
        RAW_BARRIER();       // #1: staged data visible to all waves

        // next tile's dropout bits + mask: issue now (registers) -> full iter to land
        uint32_t dwn[4];
        #pragma unroll
        for (int i = 0; i < 4; ++i) dwn[i] = dub[i*32 + tn];
        int mn0 = mask[b*SK + tn*TK + col];
        int mn1 = mask[b*SK + tn*TK + 16 + col];

        // ---- S = Q K^T ----
        floatx4 s0 = (floatx4){0,0,0,0}, s1 = (floatx4){0,0,0,0};
        #pragma unroll
        for (int c = 0; c < 8; ++c) {
            const int g0 = c*4 + quad;
            const int r0 = col, r1 = col + 16;
            bf16x8 kf0 = *(const bf16x8*)(KsB + r0*512 + ((g0 ^ (r0 & 7)) * 16));
            bf16x8 kf1 = *(const bf16x8*)(KsB + r1*512 + ((g0 ^ (r1 & 7)) * 16));
            s0 = __builtin_amdgcn_mfma_f32_16x16x32_bf16(qf[c], kf0, s0, 0,0,0);
            s1 = __builtin_amdgcn_mfma_f32_16x16x32_bf16(qf[c], kf1, s1, 0,0,0);
        }

        // ---- online softmax (defer-max) + dropout + Ps write ----
        const float mm0 = mcur0 ? 0.f : NMASK;
        const float mm1 = mcur1 ? 0.f : NMASK;
        float sv0[4], sv1[4], mxr[4];
        #pragma unroll
        for (int i = 0; i < 4; ++i) {
            sv0[i] = s0[i] + mm0;
            sv1[i] = s1[i] + mm1;
            mxr[i] = rowmax16(fmaxf(sv0[i], sv1[i]));
        }
        float g = mxr[0] - m_i[0];
        g = fmaxf(g, mxr[1] - m_i[1]);
        g = fmaxf(g, mxr[2] - m_i[2]);
        g = fmaxf(g, mxr[3] - m_i[3]);
        if (__any(g > DEFER_THR)) {          // wave-uniform; no barriers inside
            float alpha[4];
            #pragma unroll
            for (int i = 0; i < 4; ++i) {
                float mnew = fmaxf(m_i[i], mxr[i]);
                alpha[i] = __expf(m_i[i] - mnew);
                m_i[i] = mnew;
                l_i[i] *= alpha[i];
            }
            floatx4 av = {alpha[0], alpha[1], alpha[2], alpha[3]};
            #pragma unroll
            for (int blk = 0; blk < 16; ++blk) o_acc[blk] *= av;
        }
        #pragma unroll
        for (int i = 0; i < 4; ++i) {
            float p0 = __expf(sv0[i] - m_i[i]);
            float p1 = __expf(sv1[i] - m_i[i]);
            float rs = rowsum16(p0 + p1);
            l_i[i] += rs;                     // softmax denom uses pre-dropout p

            uint32_t wb = dwc[i];
            p0 = ((wb >> col) & 1u)        ? p0 * KEEP_F : 0.f;
            p1 = ((wb >> (col + 16)) & 1u) ? p1 * KEEP_F : 0.f;

            const int row = wave*16 + quad*4 + i;
            const int k0 = col, k1 = col + 16;
            *(bf16_t*)(PsB + row*64 + (((k0>>3) ^ ((row>>1) & 3)) * 16) + (k0 & 7)*2) = (bf16_t)p0;
            *(bf16_t*)(PsB + row*64 + (((k1>>3) ^ ((row>>1) & 3)) * 16) + (k1 & 7)*2) = (bf16_t)p1;
        }

        WAIT_LGKM0();
        RAW_BARRIER();       // #2: all waves done reading Ks[kt] -> region free
        ISSUE_K(tn);         // Ks[kt+1] in flight across PV phase

        WAIT_VM(10);         // drain Vt[kt] (leave dwn+mask(6) + Ks[kt+1](4) in flight)
        RAW_BARRIER();       // #3: Vt[kt] visible to all waves

        // ---- O += P V ----
        {
            const int prow = wave*16 + col;
            bf16x8 pf = *(const bf16x8*)(PsB + prow*64 + ((quad ^ ((prow>>1) & 3)) * 16));
            #pragma unroll
            for (int blk = 0; blk < 16; ++blk) {
                const int dv = blk*16 + col;
                bf16x8 vf = *(const bf16x8*)(VtB + dv*64 + ((quad ^ ((dv>>1) & 3)) * 16));
                o_acc[blk] = __builtin_amdgcn_mfma_f32_16x16x32_bf16(pf, vf, o_acc[blk], 0,0,0);
            }
        }

        WAIT_LGKM0();
        RAW_BARRIER();       // #4: all waves done reading Vt[kt] -> region free
        ISSUE_V(tn);         // Vt[kt+1] in flight across next S+softmax

        #pragma unroll
        for (int i = 0; i < 4; ++i) dwc[i] = dwn[i];
        mcur0 = mn0; mcur1 = mn1;
    }
    WAIT_VM(0);              // drain trailing redundant prefetches before LDS dealloc

    // ---- epilogue ----
    float inv_l[4];
    #pragma unroll
    for (int i = 0; i < 4; ++i) inv_l[i] = 1.f / l_i[i];
    float* op = out + ((size_t)(b*SQ + qt*64 + wave*16 + quad*4))*DV + col;
    #pragma unroll
    for (int blk = 0; blk < 16; ++blk) {
        #pragma unroll
        for (int i = 0; i < 4; ++i)
            op[(size_t)i*DV + blk*16] = o_acc[blk][i] * inv_l[i];
    }
    #undef ISSUE_K
    #undef ISSUE_V
}

extern "C" void kernel_launch(void* const* d_in, const int* in_sizes, int n_in,
                              void* d_out, int out_size, void* d_ws, size_t ws_size,
                              hipStream_t stream) {
    const float* q    = (const float*)d_in[0];
    const float* k    = (const float*)d_in[1];
    const float* v    = (const float*)d_in[2];
    const int*   mask = (const int*)d_in[3];
    const float* du   = (const float*)d_in[4];
    float* out = (float*)d_out;

    bf16_t*   ktiles = (bf16_t*)d_ws;                              // 32 MB
    bf16_t*   vtiles = (bf16_t*)((char*)d_ws + (size_t)33554432);  // 32 MB
    uint32_t* dubits = (uint32_t*)((char*)d_ws + (size_t)67108864); // 8 MB keep-bit mask

    hipLaunchKernelGGL(prepass, dim3(6144), dim3(256), 0, stream, k, v, du, ktiles, vtiles, dubits);
    hipLaunchKernelGGL(attn_main, dim3(B_ * (SQ/64)), dim3(256), 0, stream,
                       q, mask, dubits, ktiles, vtiles, out);
}

// Round 2
// 729.196 us; speedup vs baseline: 1.0627x; 1.0627x over previous
//
#include <hip/hip_runtime.h>
#include <hip/hip_bf16.h>
#include <stdint.h>

typedef __bf16 bf16_t;
typedef bf16_t bf16x8 __attribute__((ext_vector_type(8)));
typedef bf16_t bf16x4 __attribute__((ext_vector_type(4)));
typedef float floatx4 __attribute__((ext_vector_type(4)));
typedef uint32_t uint32x4 __attribute__((ext_vector_type(4)));

#define B_  64
#define SQ  1024
#define SK  1024
#define D_  256
#define DV  256
#define TK  32
#define NT  32
#define SCALE_F 0.0625f
#define NMASK   (-1.0e9f)
#define KEEP_F  (1.0f/0.9f)
#define THRESH  0.1f
#define DEFER_THR 3.0f   // skip o_acc rescale unless row-max grows by > this (p <= e^3, fine in bf16)

#define AS1(p) ((const __attribute__((address_space(1))) uint32_t*)(p))
#define AS3(p) ((__attribute__((address_space(3))) uint32_t*)(p))

#define RAW_BARRIER() __asm__ volatile("s_barrier" ::: "memory")
#define WAIT_VM(N)    __asm__ volatile("s_waitcnt vmcnt(" #N ")" ::: "memory")
#define WAIT_LGKM0()  __asm__ volatile("s_waitcnt lgkmcnt(0)" ::: "memory")

__device__ __forceinline__ void gload16(const void* g, void* lds) {
    // async global->LDS, 16B/lane; LDS base is wave-uniform, HW adds lane*16
    __builtin_amdgcn_global_load_lds(AS1(g), AS3(lds), 16, 0, 0);
}

template<int CTRL>
__device__ __forceinline__ float dpp_f(float x) {
    int y = __builtin_amdgcn_update_dpp(0, __float_as_int(x), CTRL, 0xF, 0xF, true);
    return __int_as_float(y);
}
// reductions over 16 contiguous lanes (one DPP "row") — VALU pipe, no LDS
__device__ __forceinline__ float rowsum16(float v) {
    v += dpp_f<0x128>(v);   // row_ror:8
    v += dpp_f<0x124>(v);   // row_ror:4
    v += dpp_f<0x4E>(v);    // quad_perm(2,3,0,1)
    v += dpp_f<0xB1>(v);    // quad_perm(1,0,3,2)
    return v;
}
__device__ __forceinline__ float rowmax16(float v) {
    v = fmaxf(v, dpp_f<0x128>(v));
    v = fmaxf(v, dpp_f<0x124>(v));
    v = fmaxf(v, dpp_f<0x4E>(v));
    v = fmaxf(v, dpp_f<0xB1>(v));
    return v;
}

// ---------------- pre-pass ----------------
// bid <  2048 : K fp32 -> bf16 swizzled tiles
// bid <  4096 : V fp32 -> bf16 transposed swizzled tiles
// bid >= 4096 : drop_u fp32 -> keep-bit mask, TILE-MAJOR layout:
//               dubits[ qblock*2048 + kt*64 + row64 ], qblock = (b*SQ+row)/64.
//               bit j of word = (du[b][row][kt*32+j] >= 0.1).
//               Per attn iteration a block reads 64 CONTIGUOUS words (2 full lines).
__global__ __launch_bounds__(256) void prepass(
    const float* __restrict__ k, const float* __restrict__ v, const float* __restrict__ du,
    bf16_t* __restrict__ ktiles, bf16_t* __restrict__ vtiles, uint32_t* __restrict__ dubits)
{
    __shared__ bf16_t Vls[32 * 258];   // padded transpose staging
    const int bid = blockIdx.x;
    const int tid = threadIdx.x;
    if (bid < 2048) {
        const int r = tid >> 3;
        const float* src = k + ((size_t)(bid * 32 + r)) * D_ + (tid & 7) * 32;
        char* dst = (char*)ktiles + ((size_t)bid) * 16384;
        #pragma unroll
        for (int gl = 0; gl < 4; ++gl) {
            float4 a = *(const float4*)(src + gl * 8);
            float4 b4 = *(const float4*)(src + gl * 8 + 4);
            bf16x8 f;
            f[0]=(bf16_t)a.x;  f[1]=(bf16_t)a.y;  f[2]=(bf16_t)a.z;  f[3]=(bf16_t)a.w;
            f[4]=(bf16_t)b4.x; f[5]=(bf16_t)b4.y; f[6]=(bf16_t)b4.z; f[7]=(bf16_t)b4.w;
            int g = (tid & 7) * 4 + gl;
            *(bf16x8*)(dst + r * 512 + ((g ^ (r & 7)) * 16)) = f;
        }
    } else if (bid < 4096) {
        const int bid2 = bid - 2048;
        const int kk = tid >> 3, dv0 = (tid & 7) * 32;
        const float* src = v + ((size_t)(bid2 * 32 + kk)) * DV + dv0;
        #pragma unroll
        for (int j = 0; j < 8; ++j) {
            float4 a = *(const float4*)(src + j * 4);
            bf16x4 f4;
            f4[0]=(bf16_t)a.x; f4[1]=(bf16_t)a.y; f4[2]=(bf16_t)a.z; f4[3]=(bf16_t)a.w;
            *(bf16x4*)(&Vls[kk * 258 + dv0 + j * 4]) = f4;
        }
        __syncthreads();
        char* dst = (char*)vtiles + ((size_t)bid2) * 16384;
        #pragma unroll
        for (int c = 0; c < 4; ++c) {
            int dv = c * 64 + (tid >> 2);
            int gphys = tid & 3;
            int glog = gphys ^ ((dv >> 1) & 3);
            bf16x8 f;
            #pragma unroll
            for (int jj = 0; jj < 8; ++jj) f[jj] = Vls[(glog * 8 + jj) * 258 + dv];
            *(bf16x8*)(dst + dv * 64 + gphys * 16) = f;
        }
    } else {
        // dropout bit-pack: thread handles 4 consecutive kt-words of one row; write transposed
        const int w0  = (bid - 4096) * 1024 + tid * 4;   // linear word index (row-major)
        const int R   = w0 >> 5;                          // global row = b*SQ + row
        const int kt0 = w0 & 31;
        const float* src = du + (size_t)w0 * 32;
        uint32_t* dstp = dubits + ((size_t)(R >> 6)) * 2048 + (R & 63);
        #pragma unroll
        for (int j = 0; j < 4; ++j) {
            uint32_t m = 0;
            #pragma unroll
            for (int e = 0; e < 32; e += 4) {
                float4 f = *(const float4*)(src + j * 32 + e);
                m |= (f.x >= THRESH ? 1u : 0u) << e;
                m |= (f.y >= THRESH ? 1u : 0u) << (e + 1);
                m |= (f.z >= THRESH ? 1u : 0u) << (e + 2);
                m |= (f.w >= THRESH ? 1u : 0u) << (e + 3);
            }
            dstp[(kt0 + j) * 64] = m;
        }
    }
}

// ---------------- main fused attention ----------------
// LDS: Ks 16KB @0 | Vt 16KB @16384 | Ps 4KB @32768  = 36KB -> 4 blocks/CU (grid 1024 = 256 CU x 4, no tail)
__global__ __launch_bounds__(256, 4) void attn_main(
    const float* __restrict__ q, const int* __restrict__ mask,
    const uint32_t* __restrict__ dubits, const bf16_t* __restrict__ ktiles,
    const bf16_t* __restrict__ vtiles, float* __restrict__ out)
{
    __shared__ char smem[36864];
    char* KsB = smem;
    char* VtB = smem + 16384;
    char* PsB = smem + 32768;

    // XCD-aware bijective swizzle (grid 1024 % 8 == 0): all 16 q-blocks of a batch
    // land on ONE XCD -> K/V tile re-reads hit the per-XCD 4MB L2.
    const int bid_hw = blockIdx.x;
    const int bid    = ((bid_hw & 7) << 7) | (bid_hw >> 3);
    const int b    = bid >> 4;
    const int qt   = bid & 15;
    const int tid  = threadIdx.x;
    const int wave = tid >> 6;
    const int lane = tid & 63;
    const int col  = lane & 15;
    const int quad = lane >> 4;

    // Q fragments (A-layout), SCALE folded in before bf16 cvt
    bf16x8 qf[8];
    {
        const float* qp = q + ((size_t)(b*SQ + qt*64 + wave*16 + col))*D_ + quad*8;
        #pragma unroll
        for (int c = 0; c < 8; ++c) {
            float4 a  = *(const float4*)(qp + c*32);
            float4 b4 = *(const float4*)(qp + c*32 + 4);
            bf16x8 f;
            f[0]=(bf16_t)(a.x*SCALE_F);  f[1]=(bf16_t)(a.y*SCALE_F);
            f[2]=(bf16_t)(a.z*SCALE_F);  f[3]=(bf16_t)(a.w*SCALE_F);
            f[4]=(bf16_t)(b4.x*SCALE_F); f[5]=(bf16_t)(b4.y*SCALE_F);
            f[6]=(bf16_t)(b4.z*SCALE_F); f[7]=(bf16_t)(b4.w*SCALE_F);
            qf[c] = f;
        }
    }

    floatx4 o_acc[16];
    #pragma unroll
    for (int i = 0; i < 16; ++i) o_acc[i] = (floatx4){0.f,0.f,0.f,0.f};
    float m_i[4] = {-1e30f,-1e30f,-1e30f,-1e30f};
    float l_i[4] = {0.f,0.f,0.f,0.f};

    const size_t tbase = (size_t)(b * NT) * 16384;
    // tile-major dropout bits: this lane's 4 rows (quad*4+i) are CONSECUTIVE words
    // -> single dwordx4 per tile (1 VMEM op; vmcnt ledger below relies on this)
    const uint32x4* dubv = (const uint32x4*)(dubits
        + ((size_t)(b*16 + qt)) * 2048 + wave*16 + quad*4);

    // --- staging issue helpers (4 waves share each tile; 4/4 instrs per wave) ---
    #define ISSUE_K(t) do { \
        const char* g_ = (const char*)ktiles + tbase + (size_t)(t)*16384 + wave*4096 + lane*16; \
        char* l_ = KsB + wave*4096; \
        gload16(g_, l_); gload16(g_+1024, l_+1024); \
        gload16(g_+2048, l_+2048); gload16(g_+3072, l_+3072); } while(0)

    #define ISSUE_V(t) do { \
        const char* g_ = (const char*)vtiles + tbase + (size_t)(t)*16384 + wave*4096 + lane*16; \
        char* l_ = VtB + wave*4096; \
        gload16(g_, l_); gload16(g_+1024, l_+1024); \
        gload16(g_+2048, l_+2048); gload16(g_+3072, l_+3072); } while(0)

    // preamble: tile 0 in flight  (order: Ks(4), dubits(1), mask(2), Vt(4))
    ISSUE_K(0);
    uint32x4 dwc = dubv[0];
    int mcur0 = mask[b*SK + col];
    int mcur1 = mask[b*SK + 16 + col];
    ISSUE_V(0);

    for (int kt = 0; kt < NT; ++kt) {
        const int tn = (kt + 1 < NT) ? kt + 1 : NT - 1;   // clamp -> constant vmcnt counts

        WAIT_VM(4);          // Ks[kt], dubits[kt], mask landed; Vt[kt](4) still in flight
        RAW_BARRIER();       // #1: staged data visible to all waves

        // next tile's dropout bits + mask: issue now (registers) -> full iter to land
        uint32x4 dwn = dubv[tn * 16];     // 16 x uint32x4 = 64 words per tile
        int mn0 = mask[b*SK + tn*TK + col];
        int mn1 = mask[b*SK + tn*TK + 16 + col];

        // ---- S = Q K^T ----
        floatx4 s0 = (floatx4){0,0,0,0}, s1 = (floatx4){0,0,0,0};
        #pragma unroll
        for (int c = 0; c < 8; ++c) {
            const int g0 = c*4 + quad;
            const int r0 = col, r1 = col + 16;
            bf16x8 kf0 = *(const bf16x8*)(KsB + r0*512 + ((g0 ^ (r0 & 7)) * 16));
            bf16x8 kf1 = *(const bf16x8*)(KsB + r1*512 + ((g0 ^ (r1 & 7)) * 16));
            s0 = __builtin_amdgcn_mfma_f32_16x16x32_bf16(qf[c], kf0, s0, 0,0,0);
            s1 = __builtin_amdgcn_mfma_f32_16x16x32_bf16(qf[c], kf1, s1, 0,0,0);
        }

        // ---- online softmax (defer-max) + dropout + Ps write ----
        const float mm0 = mcur0 ? 0.f : NMASK;
        const float mm1 = mcur1 ? 0.f : NMASK;
        float sv0[4], sv1[4], mxr[4];
        #pragma unroll
        for (int i = 0; i < 4; ++i) {
            sv0[i] = s0[i] + mm0;
            sv1[i] = s1[i] + mm1;
            mxr[i] = rowmax16(fmaxf(sv0[i], sv1[i]));
        }
        float g = mxr[0] - m_i[0];
        g = fmaxf(g, mxr[1] - m_i[1]);
        g = fmaxf(g, mxr[2] - m_i[2]);
        g = fmaxf(g, mxr[3] - m_i[3]);
        if (__any(g > DEFER_THR)) {          // wave-uniform; no barriers inside
            float alpha[4];
            #pragma unroll
            for (int i = 0; i < 4; ++i) {
                float mnew = fmaxf(m_i[i], mxr[i]);
                alpha[i] = __expf(m_i[i] - mnew);
                m_i[i] = mnew;
                l_i[i] *= alpha[i];
            }
            floatx4 av = {alpha[0], alpha[1], alpha[2], alpha[3]};
            #pragma unroll
            for (int blk = 0; blk < 16; ++blk) o_acc[blk] *= av;
        }
        #pragma unroll
        for (int i = 0; i < 4; ++i) {
            float p0 = __expf(sv0[i] - m_i[i]);
            float p1 = __expf(sv1[i] - m_i[i]);
            float rs = rowsum16(p0 + p1);
            l_i[i] += rs;                     // softmax denom uses pre-dropout p

            uint32_t wb = dwc[i];
            p0 = ((wb >> col) & 1u)        ? p0 * KEEP_F : 0.f;
            p1 = ((wb >> (col + 16)) & 1u) ? p1 * KEEP_F : 0.f;

            const int row = wave*16 + quad*4 + i;
            const int k0 = col, k1 = col + 16;
            *(bf16_t*)(PsB + row*64 + (((k0>>3) ^ ((row>>1) & 3)) * 16) + (k0 & 7)*2) = (bf16_t)p0;
            *(bf16_t*)(PsB + row*64 + (((k1>>3) ^ ((row>>1) & 3)) * 16) + (k1 & 7)*2) = (bf16_t)p1;
        }

        WAIT_LGKM0();
        RAW_BARRIER();       // #2: all waves done reading Ks[kt] -> region free
        ISSUE_K(tn);         // Ks[kt+1] in flight across PV phase

        WAIT_VM(7);          // drain Vt[kt](4); leave dwn(1)+mask(2)+Ks[kt+1](4) in flight
        RAW_BARRIER();       // #3: Vt[kt] visible to all waves

        // ---- O += P V ----
        {
            const int prow = wave*16 + col;
            bf16x8 pf = *(const bf16x8*)(PsB + prow*64 + ((quad ^ ((prow>>1) & 3)) * 16));
            #pragma unroll
            for (int blk = 0; blk < 16; ++blk) {
                const int dv = blk*16 + col;
                bf16x8 vf = *(const bf16x8*)(VtB + dv*64 + ((quad ^ ((dv>>1) & 3)) * 16));
                o_acc[blk] = __builtin_amdgcn_mfma_f32_16x16x32_bf16(pf, vf, o_acc[blk], 0,0,0);
            }
        }

        WAIT_LGKM0();
        RAW_BARRIER();       // #4: all waves done reading Vt[kt] -> region free
        ISSUE_V(tn);         // Vt[kt+1] in flight across next S+softmax

        dwc = dwn;
        mcur0 = mn0; mcur1 = mn1;
    }
    WAIT_VM(0);              // drain trailing redundant prefetches before LDS dealloc

    // ---- epilogue ----
    float inv_l[4];
    #pragma unroll
    for (int i = 0; i < 4; ++i) inv_l[i] = 1.f / l_i[i];
    float* op = out + ((size_t)(b*SQ + qt*64 + wave*16 + quad*4))*DV + col;
    #pragma unroll
    for (int blk = 0; blk < 16; ++blk) {
        #pragma unroll
        for (int i = 0; i < 4; ++i)
            op[(size_t)i*DV + blk*16] = o_acc[blk][i] * inv_l[i];
    }
    #undef ISSUE_K
    #undef ISSUE_V
}

extern "C" void kernel_launch(void* const* d_in, const int* in_sizes, int n_in,
                              void* d_out, int out_size, void* d_ws, size_t ws_size,
                              hipStream_t stream) {
    const float* q    = (const float*)d_in[0];
    const float* k    = (const float*)d_in[1];
    const float* v    = (const float*)d_in[2];
    const int*   mask = (const int*)d_in[3];
    const float* du   = (const float*)d_in[4];
    float* out = (float*)d_out;

    bf16_t*   ktiles = (bf16_t*)d_ws;                              // 32 MB
    bf16_t*   vtiles = (bf16_t*)((char*)d_ws + (size_t)33554432);  // 32 MB
    uint32_t* dubits = (uint32_t*)((char*)d_ws + (size_t)67108864); // 8 MB keep-bit mask (tile-major)

    hipLaunchKernelGGL(prepass, dim3(6144), dim3(256), 0, stream, k, v, du, ktiles, vtiles, dubits);
    hipLaunchKernelGGL(attn_main, dim3(B_ * (SQ/64)), dim3(256), 0, stream,
                       q, mask, dubits, ktiles, vtiles, out);
}